// Round 1
// baseline (12095.597 us; speedup 1.0000x reference)
//
#include <hip/hip_runtime.h>
#include <cstddef>

#define RR 128
#define CC 256
#define HW 784

// ---------------- weight transposes ----------------
__global__ void k_tw_conv1(const float* __restrict__ w, float* __restrict__ wt) {
  int i = blockIdx.x * 256 + threadIdx.x;
  if (i >= 9 * 259 * 256) return;
  int oc = i & 255, rest = i >> 8;
  int ic = rest % 259, kq = rest / 259;
  wt[i] = w[(oc * 259 + ic) * 9 + kq];
}
__global__ void k_tw_convs(const float* __restrict__ w, float* __restrict__ wt) {
  int i = blockIdx.x * 256 + threadIdx.x;
  if (i >= 3 * 9 * 256 * 256) return;
  int oc = i & 255, rest = i >> 8;
  int ic = rest & 255, rest2 = rest >> 8;
  int kq = rest2 % 9, l = rest2 / 9;
  wt[i] = w[(((l * 256 + oc) * 256 + ic) * 9) + kq];
}
__global__ void k_tw_deconv(const float* __restrict__ w, float* __restrict__ wt) {
  int i = blockIdx.x * 256 + threadIdx.x;
  if (i >= 4 * 256 * 256) return;
  int oc = i & 255, rest = i >> 8;
  int ic = rest & 255, kl = rest >> 8;
  wt[i] = w[(ic * 256 + oc) * 4 + kl];
}
__global__ void k_tw_conv2(const float* __restrict__ w, float* __restrict__ wt) {
  int i = blockIdx.x * 256 + threadIdx.x;
  if (i >= 256 * 256) return;
  int oc = i & 255, ic = i >> 8;
  wt[i] = w[oc * 256 + ic];
}

// ---------------- bilinear resize 56->28 (jax.image.resize, antialias) -------
__device__ inline int resize_taps(int i, int* rows, float* wts) {
  if (i == 0) {
    rows[0] = 0; rows[1] = 1; rows[2] = 2;
    wts[0] = 3.f / 7.f; wts[1] = 3.f / 7.f; wts[2] = 1.f / 7.f; return 3;
  }
  if (i == 27) {
    rows[0] = 53; rows[1] = 54; rows[2] = 55;
    wts[0] = 1.f / 7.f; wts[1] = 3.f / 7.f; wts[2] = 3.f / 7.f; return 3;
  }
  rows[0] = 2 * i - 1; rows[1] = 2 * i; rows[2] = 2 * i + 1; rows[3] = 2 * i + 2;
  wts[0] = 0.125f; wts[1] = 0.375f; wts[2] = 0.375f; wts[3] = 0.125f; return 4;
}

__global__ __launch_bounds__(256) void k_resize(
    const float* __restrict__ ma_in, const float* __restrict__ mb_in,
    float* __restrict__ m_a28, float* __restrict__ m_b28,
    float* __restrict__ ma_sum) {
  int r = blockIdx.x, side = blockIdx.y, t = threadIdx.x;
  const float* in = (side ? mb_in : ma_in) + (size_t)r * 3136;
  float* out = (side ? m_b28 : m_a28) + (size_t)r * 784;
  float cnt = 0.f;
  for (int p = t; p < 784; p += 256) {
    int i = p / 28, j = p % 28;
    int rr_[4], cc_[4]; float wr[4], wc[4];
    int nr = resize_taps(i, rr_, wr), nc = resize_taps(j, cc_, wc);
    float v = 0.f;
    for (int a = 0; a < nr; ++a) {
      float rv = 0.f;
      for (int b = 0; b < nc; ++b) rv += wc[b] * in[rr_[a] * 56 + cc_[b]];
      v += wr[a] * rv;
    }
    out[p] = v;
    cnt += (v >= 0.f) ? 1.f : 0.f;
  }
  __shared__ float red[4];
  for (int off = 32; off; off >>= 1) cnt += __shfl_xor(cnt, off, 64);
  int lane = t & 63, wid = t >> 6;
  if (lane == 0) red[wid] = cnt;
  __syncthreads();
  if (t == 0 && side == 0) ma_sum[r] = red[0] + red[1] + red[2] + red[3];
}

// ---------------- gap + conv2(gap) ----------------
__global__ __launch_bounds__(256) void k_gap(
    const float* __restrict__ feat_a, const float* __restrict__ m_a28,
    const float* __restrict__ ma_sum, float* __restrict__ gap) {
  int r = blockIdx.y, wid = threadIdx.x >> 6, lane = threadIdx.x & 63;
  int c = blockIdx.x * 4 + wid;
  const float* x = feat_a + ((size_t)r * 256 + c) * 784;
  const float* m = m_a28 + (size_t)r * 784;
  float s = 0.f;
  for (int n = lane; n < 784; n += 64)
    s += x[n] * ((m[n] >= 0.f) ? 1.f : 0.f);
  for (int off = 32; off; off >>= 1) s += __shfl_xor(s, off, 64);
  if (lane == 0) gap[r * 256 + c] = s / (ma_sum[r] + 1e-5f);
}

__global__ __launch_bounds__(256) void k_gap2(
    const float* __restrict__ gap, const float* __restrict__ w2t,
    const float* __restrict__ b2, float* __restrict__ gap2) {
  int r = blockIdx.x, t = threadIdx.x;
  __shared__ float g[256];
  g[t] = gap[r * 256 + t];
  __syncthreads();
  float acc = b2[t];
  for (int ic = 0; ic < 256; ++ic) acc += w2t[ic * 256 + t] * g[ic];
  gap2[r * 256 + t] = acc;
}

// ---------------- EM + prop ----------------
__device__ inline void block_sum8(float v[8], float (*redsh)[8], float* cs,
                                  int t, int lane, int wid) {
#pragma unroll
  for (int k = 0; k < 8; ++k)
    for (int off = 32; off; off >>= 1) v[k] += __shfl_xor(v[k], off, 64);
  if (lane == 0) {
#pragma unroll
    for (int k = 0; k < 8; ++k) redsh[wid][k] = v[k];
  }
  __syncthreads();
  if (t < 8) {
    float s = 0.f;
#pragma unroll
    for (int w = 0; w < 8; ++w) s += redsh[w][t];
    cs[t] = s;
  }
  __syncthreads();
}

__global__ __launch_bounds__(512) void k_em(
    const float* __restrict__ feat_a, const float* __restrict__ feat_b,
    const float* __restrict__ pos_mu, const float* __restrict__ neg_mu,
    const float* __restrict__ m_a28, const float* __restrict__ m_b28,
    float* __restrict__ pos_z, float* __restrict__ neg_z) {
  __shared__ __align__(16) float mu[256][8];
  __shared__ __align__(16) float munew[256][8];
  __shared__ __align__(16) float zsh[784][8];
  __shared__ float redsh[8][8];
  __shared__ float cs[8];
  int r = blockIdx.x, t = threadIdx.x;
  int lane = t & 63, wid = t >> 6;
  int n0 = t, n1 = t + 512;
  bool has1 = (n1 < 784);
  if (t < 256) {
#pragma unroll
    for (int k = 0; k < 4; ++k) {
      mu[t][k] = pos_mu[t * 4 + k];
      mu[t][k + 4] = neg_mu[t * 4 + k];
    }
  }
  for (int phase = 0; phase < 2; ++phase) {
    const float* x = (phase ? feat_b : feat_a) + (size_t)r * 200704;
    const float* mres = (phase ? m_b28 : m_a28) + (size_t)r * 784;
    float m0 = (mres[n0] >= 0.f) ? 1.f : 0.f;
    float m1 = has1 ? ((mres[n1] >= 0.f) ? 1.f : 0.f) : 0.f;
    __syncthreads();
    for (int stage = 0; stage < 6; ++stage) {
      // ---- pass A: S = x^T mu ----
      float S0[8] = {0, 0, 0, 0, 0, 0, 0, 0};
      float S1[8] = {0, 0, 0, 0, 0, 0, 0, 0};
      for (int c = 0; c < 256; ++c) {
        float4 a = *(const float4*)&mu[c][0];
        float4 b = *(const float4*)&mu[c][4];
        float x0 = x[c * 784 + n0];
        S0[0] += x0 * a.x; S0[1] += x0 * a.y; S0[2] += x0 * a.z; S0[3] += x0 * a.w;
        S0[4] += x0 * b.x; S0[5] += x0 * b.y; S0[6] += x0 * b.z; S0[7] += x0 * b.w;
        if (has1) {
          float x1 = x[c * 784 + n1];
          S1[0] += x1 * a.x; S1[1] += x1 * a.y; S1[2] += x1 * a.z; S1[3] += x1 * a.w;
          S1[4] += x1 * b.x; S1[5] += x1 * b.y; S1[6] += x1 * b.z; S1[7] += x1 * b.w;
        }
      }
      float ps[8];
#pragma unroll
      for (int k = 0; k < 8; ++k) ps[k] = 0.f;
      {
        float mxp = fmaxf(fmaxf(S0[0], S0[1]), fmaxf(S0[2], S0[3]));
        float e0 = expf(20.f * (S0[0] - mxp)), e1 = expf(20.f * (S0[1] - mxp));
        float e2 = expf(20.f * (S0[2] - mxp)), e3 = expf(20.f * (S0[3] - mxp));
        float dp = e0 + e1 + e2 + e3;
        float mxn = fmaxf(fmaxf(S0[4], S0[5]), fmaxf(S0[6], S0[7]));
        float f0 = expf(20.f * (S0[4] - mxn)), f1 = expf(20.f * (S0[5] - mxn));
        float f2 = expf(20.f * (S0[6] - mxn)), f3 = expf(20.f * (S0[7] - mxn));
        float dn = f0 + f1 + f2 + f3;
        float im = 1.f - m0;
        float z0 = e0 / dp * m0, z1 = e1 / dp * m0, z2 = e2 / dp * m0, z3 = e3 / dp * m0;
        float z4 = f0 / dn * im, z5 = f1 / dn * im, z6 = f2 / dn * im, z7 = f3 / dn * im;
        zsh[n0][0] = z0; zsh[n0][1] = z1; zsh[n0][2] = z2; zsh[n0][3] = z3;
        zsh[n0][4] = z4; zsh[n0][5] = z5; zsh[n0][6] = z6; zsh[n0][7] = z7;
        ps[0] += z0; ps[1] += z1; ps[2] += z2; ps[3] += z3;
        ps[4] += z4; ps[5] += z5; ps[6] += z6; ps[7] += z7;
      }
      if (has1) {
        float mxp = fmaxf(fmaxf(S1[0], S1[1]), fmaxf(S1[2], S1[3]));
        float e0 = expf(20.f * (S1[0] - mxp)), e1 = expf(20.f * (S1[1] - mxp));
        float e2 = expf(20.f * (S1[2] - mxp)), e3 = expf(20.f * (S1[3] - mxp));
        float dp = e0 + e1 + e2 + e3;
        float mxn = fmaxf(fmaxf(S1[4], S1[5]), fmaxf(S1[6], S1[7]));
        float f0 = expf(20.f * (S1[4] - mxn)), f1 = expf(20.f * (S1[5] - mxn));
        float f2 = expf(20.f * (S1[6] - mxn)), f3 = expf(20.f * (S1[7] - mxn));
        float dn = f0 + f1 + f2 + f3;
        float im = 1.f - m1;
        float z0 = e0 / dp * m1, z1 = e1 / dp * m1, z2 = e2 / dp * m1, z3 = e3 / dp * m1;
        float z4 = f0 / dn * im, z5 = f1 / dn * im, z6 = f2 / dn * im, z7 = f3 / dn * im;
        zsh[n1][0] = z0; zsh[n1][1] = z1; zsh[n1][2] = z2; zsh[n1][3] = z3;
        zsh[n1][4] = z4; zsh[n1][5] = z5; zsh[n1][6] = z6; zsh[n1][7] = z7;
        ps[0] += z0; ps[1] += z1; ps[2] += z2; ps[3] += z3;
        ps[4] += z4; ps[5] += z5; ps[6] += z6; ps[7] += z7;
      }
      block_sum8(ps, redsh, cs, t, lane, wid);
      // l1 normalize z over n
      {
        float inv[8];
#pragma unroll
        for (int k = 0; k < 8; ++k) inv[k] = 1.f / (1e-6f + cs[k]);
#pragma unroll
        for (int k = 0; k < 8; ++k) zsh[n0][k] *= inv[k];
        if (has1) {
#pragma unroll
          for (int k = 0; k < 8; ++k) zsh[n1][k] *= inv[k];
        }
      }
      __syncthreads();
      // ---- pass B: munew = x z ----
      for (int ci = 0; ci < 32; ++ci) {
        int c = wid * 32 + ci;
        float acc[8] = {0, 0, 0, 0, 0, 0, 0, 0};
        for (int n = lane; n < 784; n += 64) {
          float xv = x[c * 784 + n];
          float4 z0 = *(const float4*)&zsh[n][0];
          float4 z1 = *(const float4*)&zsh[n][4];
          acc[0] += xv * z0.x; acc[1] += xv * z0.y; acc[2] += xv * z0.z; acc[3] += xv * z0.w;
          acc[4] += xv * z1.x; acc[5] += xv * z1.y; acc[6] += xv * z1.z; acc[7] += xv * z1.w;
        }
#pragma unroll
        for (int k = 0; k < 8; ++k)
          for (int off = 32; off; off >>= 1) acc[k] += __shfl_xor(acc[k], off, 64);
        if (lane == 0) {
#pragma unroll
          for (int k = 0; k < 8; ++k) munew[c][k] = acc[k];
        }
      }
      __syncthreads();
      // ---- l2 normalize mu over c ----
      float sq[8];
      if (t < 256) {
#pragma unroll
        for (int k = 0; k < 8; ++k) { float v = munew[t][k]; sq[k] = v * v; }
      } else {
#pragma unroll
        for (int k = 0; k < 8; ++k) sq[k] = 0.f;
      }
      block_sum8(sq, redsh, cs, t, lane, wid);
      if (t < 256) {
#pragma unroll
        for (int k = 0; k < 8; ++k)
          mu[t][k] = munew[t][k] / (1e-6f + sqrtf(cs[k]));
      }
      __syncthreads();
    }
  }
  // ---- prop: z = softmax_k(mu . xb), pos/neg sums ----
  const float* xb = feat_b + (size_t)r * 200704;
  float S0[8] = {0, 0, 0, 0, 0, 0, 0, 0};
  float S1[8] = {0, 0, 0, 0, 0, 0, 0, 0};
  for (int c = 0; c < 256; ++c) {
    float4 a = *(const float4*)&mu[c][0];
    float4 b = *(const float4*)&mu[c][4];
    float x0 = xb[c * 784 + n0];
    S0[0] += x0 * a.x; S0[1] += x0 * a.y; S0[2] += x0 * a.z; S0[3] += x0 * a.w;
    S0[4] += x0 * b.x; S0[5] += x0 * b.y; S0[6] += x0 * b.z; S0[7] += x0 * b.w;
    if (has1) {
      float x1 = xb[c * 784 + n1];
      S1[0] += x1 * a.x; S1[1] += x1 * a.y; S1[2] += x1 * a.z; S1[3] += x1 * a.w;
      S1[4] += x1 * b.x; S1[5] += x1 * b.y; S1[6] += x1 * b.z; S1[7] += x1 * b.w;
    }
  }
  {
    float mx = S0[0];
#pragma unroll
    for (int k = 1; k < 8; ++k) mx = fmaxf(mx, S0[k]);
    float e[8], d = 0.f;
#pragma unroll
    for (int k = 0; k < 8; ++k) { e[k] = expf(S0[k] - mx); d += e[k]; }
    float invd = 1.f / d;
    pos_z[r * 784 + n0] = (e[0] + e[1] + e[2] + e[3]) * invd;
    neg_z[r * 784 + n0] = (e[4] + e[5] + e[6] + e[7]) * invd;
  }
  if (has1) {
    float mx = S1[0];
#pragma unroll
    for (int k = 1; k < 8; ++k) mx = fmaxf(mx, S1[k]);
    float e[8], d = 0.f;
#pragma unroll
    for (int k = 0; k < 8; ++k) { e[k] = expf(S1[k] - mx); d += e[k]; }
    float invd = 1.f / d;
    pos_z[r * 784 + n1] = (e[0] + e[1] + e[2] + e[3]) * invd;
    neg_z[r * 784 + n1] = (e[4] + e[5] + e[6] + e[7]) * invd;
  }
}

// ---------------- 3x3 conv (direct, f32) ----------------
// wt layout: [kh][kw][ic][oc], activations NCHW.
template <int CIN, bool IS_CONV1, bool RELU>
__global__ __launch_bounds__(256) void k_conv3x3(
    const float* __restrict__ x, const float* __restrict__ pz,
    const float* __restrict__ nz, const float* __restrict__ mres,
    const float* __restrict__ wt, const float* __restrict__ bias,
    const float* __restrict__ gap2, float* __restrict__ out) {
  int r = blockIdx.y, h = blockIdx.x, t = threadIdx.x;
  int wg = t >> 6, oc = (t & 63) * 4, w0 = wg * 7;
  float acc[7][4];
#pragma unroll
  for (int j = 0; j < 7; ++j)
    acc[j][0] = acc[j][1] = acc[j][2] = acc[j][3] = 0.f;
  for (int kh = 0; kh < 3; ++kh) {
    int row = h + kh - 1;
    if (row < 0 || row >= 28) continue;
    const float* wb = wt + (size_t)kh * 3 * CIN * 256 + oc;
    for (int ic = 0; ic < CIN; ++ic) {
      const float* xrow;
      if (IS_CONV1 && ic >= 256) {
        const float* e = (ic == 256) ? pz : (ic == 257) ? nz : mres;
        xrow = e + (size_t)r * 784 + row * 28;
      } else {
        xrow = x + ((size_t)r * 256 + ic) * 784 + row * 28;
      }
      float xv[9];
#pragma unroll
      for (int m2 = 0; m2 < 9; ++m2) {
        int w = w0 + m2 - 1;
        int wcl = min(max(w, 0), 27);
        float v = xrow[wcl];
        xv[m2] = (w >= 0 && w < 28) ? v : 0.f;
      }
#pragma unroll
      for (int kw = 0; kw < 3; ++kw) {
        float4 wv = *(const float4*)(wb + ((size_t)kw * CIN + ic) * 256);
#pragma unroll
        for (int j = 0; j < 7; ++j) {
          float xvv = xv[j + kw];
          acc[j][0] += xvv * wv.x; acc[j][1] += xvv * wv.y;
          acc[j][2] += xvv * wv.z; acc[j][3] += xvv * wv.w;
        }
      }
    }
  }
#pragma unroll
  for (int u = 0; u < 4; ++u) {
    float b = bias[oc + u];
    if (IS_CONV1) b += gap2[r * 256 + oc + u];
    float* o = out + (((size_t)r * 256 + oc + u) * 28 + h) * 28 + w0;
#pragma unroll
    for (int j = 0; j < 7; ++j) {
      float v = acc[j][u] + b;
      if (RELU) v = fmaxf(v, 0.f);
      o[j] = v;
    }
  }
}

// ---------------- fused deconv(2x2,s2) + relu + 1x1 logits ----------------
__global__ __launch_bounds__(256) void k_deconv_logits(
    const float* __restrict__ x, const float* __restrict__ dwt,
    const float* __restrict__ db, const float* __restrict__ wlog,
    const float* __restrict__ lb, float* __restrict__ out) {
  __shared__ float X[256 * 28];
  __shared__ float red[28][4];
  int r = blockIdx.y, h = blockIdx.x, t = threadIdx.x;
  for (int i = t; i < 7168; i += 256) {
    int ic = i / 28, w = i - ic * 28;
    X[i] = x[(size_t)r * 200704 + ic * 784 + h * 28 + w];
  }
  if (t < 112) red[t >> 2][t & 3] = 0.f;
  __syncthreads();
  int wg = t >> 6, oc = (t & 63) * 4, w0 = wg * 7;
  float b0 = db[oc], b1 = db[oc + 1], b2 = db[oc + 2], b3 = db[oc + 3];
  float l0 = wlog[oc], l1 = wlog[oc + 1], l2 = wlog[oc + 2], l3 = wlog[oc + 3];
  for (int kl = 0; kl < 4; ++kl) {
    float acc[7][4];
#pragma unroll
    for (int j = 0; j < 7; ++j)
      acc[j][0] = acc[j][1] = acc[j][2] = acc[j][3] = 0.f;
    const float* wb = dwt + (size_t)kl * 65536 + oc;
    for (int ic = 0; ic < 256; ++ic) {
      float4 wv = *(const float4*)(wb + ic * 256);
#pragma unroll
      for (int j = 0; j < 7; ++j) {
        float xv = X[ic * 28 + w0 + j];
        acc[j][0] += xv * wv.x; acc[j][1] += xv * wv.y;
        acc[j][2] += xv * wv.z; acc[j][3] += xv * wv.w;
      }
    }
#pragma unroll
    for (int j = 0; j < 7; ++j) {
      float s = l0 * fmaxf(acc[j][0] + b0, 0.f) + l1 * fmaxf(acc[j][1] + b1, 0.f) +
                l2 * fmaxf(acc[j][2] + b2, 0.f) + l3 * fmaxf(acc[j][3] + b3, 0.f);
      atomicAdd(&red[w0 + j][kl], s);
    }
  }
  __syncthreads();
  if (t < 112) {
    int w = t >> 2, kl = t & 3, k = kl >> 1, l = kl & 1;
    out[(size_t)r * 3136 + (2 * h + k) * 56 + (2 * w + l)] = red[w][kl] + lb[0];
  }
}

// ---------------- launcher ----------------
extern "C" void kernel_launch(void* const* d_in, const int* in_sizes, int n_in,
                              void* d_out, int out_size, void* d_ws, size_t ws_size,
                              hipStream_t stream) {
  const float* feat_a = (const float*)d_in[0];
  const float* mask_a = (const float*)d_in[1];
  const float* feat_b = (const float*)d_in[2];
  const float* mask_b = (const float*)d_in[3];
  const float* pos_mu = (const float*)d_in[4];
  const float* neg_mu = (const float*)d_in[5];
  const float* conv1_w = (const float*)d_in[6];
  const float* conv1_b = (const float*)d_in[7];
  const float* conv2_w = (const float*)d_in[8];
  const float* conv2_b = (const float*)d_in[9];
  const float* convs_w = (const float*)d_in[10];
  const float* convs_b = (const float*)d_in[11];
  const float* deconv_w = (const float*)d_in[12];
  const float* deconv_b = (const float*)d_in[13];
  const float* logits_w = (const float*)d_in[14];
  const float* logits_b = (const float*)d_in[15];
  float* out = (float*)d_out;
  float* ws = (float*)d_ws;

  // workspace layout (floats)
  float* m_a28 = ws;                 // 100352
  float* m_b28 = m_a28 + 100352;     // 100352
  float* ma_sum = m_b28 + 100352;    // 128 (pad 128)
  float* gap = ma_sum + 128;         // 32768
  float* gap2 = gap + 32768;         // 32768
  float* pos_z = gap2 + 32768;       // 100352
  float* neg_z = pos_z + 100352;     // 100352
  float* w1t = neg_z + 100352;       // 596736
  float* w3t = w1t + 596736;         // 1769472
  float* dwt = w3t + 1769472;        // 262144
  float* w2t = dwt + 262144;         // 65536
  float* x0 = w2t + 65536;           // 25690112
  float* x1 = x0 + 25690112;         // 25690112

  k_tw_conv1<<<(9 * 259 * 256 + 255) / 256, 256, 0, stream>>>(conv1_w, w1t);
  k_tw_convs<<<(3 * 9 * 256 * 256 + 255) / 256, 256, 0, stream>>>(convs_w, w3t);
  k_tw_deconv<<<(4 * 256 * 256 + 255) / 256, 256, 0, stream>>>(deconv_w, dwt);
  k_tw_conv2<<<(256 * 256 + 255) / 256, 256, 0, stream>>>(conv2_w, w2t);

  k_resize<<<dim3(128, 2), 256, 0, stream>>>(mask_a, mask_b, m_a28, m_b28, ma_sum);
  k_gap<<<dim3(64, 128), 256, 0, stream>>>(feat_a, m_a28, ma_sum, gap);
  k_gap2<<<128, 256, 0, stream>>>(gap, w2t, conv2_b, gap2);
  k_em<<<128, 512, 0, stream>>>(feat_a, feat_b, pos_mu, neg_mu, m_a28, m_b28,
                                pos_z, neg_z);

  // conv1 + gap2 broadcast (no relu)
  k_conv3x3<259, true, false><<<dim3(28, 128), 256, 0, stream>>>(
      feat_b, pos_z, neg_z, m_a28, w1t, conv1_b, gap2, x0);
  // 3x relu convs, ping-pong
  k_conv3x3<256, false, true><<<dim3(28, 128), 256, 0, stream>>>(
      x0, nullptr, nullptr, nullptr, w3t + (size_t)0 * 9 * 256 * 256,
      convs_b + 0 * 256, nullptr, x1);
  k_conv3x3<256, false, true><<<dim3(28, 128), 256, 0, stream>>>(
      x1, nullptr, nullptr, nullptr, w3t + (size_t)1 * 9 * 256 * 256,
      convs_b + 1 * 256, nullptr, x0);
  k_conv3x3<256, false, true><<<dim3(28, 128), 256, 0, stream>>>(
      x0, nullptr, nullptr, nullptr, w3t + (size_t)2 * 9 * 256 * 256,
      convs_b + 2 * 256, nullptr, x1);

  k_deconv_logits<<<dim3(28, 128), 256, 0, stream>>>(x1, dwt, deconv_b,
                                                     logits_w, logits_b, out);
}

// Round 2
// 7489.570 us; speedup vs baseline: 1.6150x; 1.6150x over previous
//
#include <hip/hip_runtime.h>
#include <cstddef>

// ---------------- weight transposes ----------------
__global__ void k_tw_conv1(const float* __restrict__ w, float* __restrict__ wt) {
  int i = blockIdx.x * 256 + threadIdx.x;
  if (i >= 9 * 259 * 256) return;
  int oc = i & 255, rest = i >> 8;
  int ic = rest % 259, kq = rest / 259;
  wt[i] = w[(oc * 259 + ic) * 9 + kq];
}
__global__ void k_tw_convs(const float* __restrict__ w, float* __restrict__ wt) {
  int i = blockIdx.x * 256 + threadIdx.x;
  if (i >= 3 * 9 * 256 * 256) return;
  int oc = i & 255, rest = i >> 8;
  int ic = rest & 255, rest2 = rest >> 8;
  int kq = rest2 % 9, l = rest2 / 9;
  wt[i] = w[(((l * 256 + oc) * 256 + ic) * 9) + kq];
}
__global__ void k_tw_deconv(const float* __restrict__ w, float* __restrict__ wt) {
  int i = blockIdx.x * 256 + threadIdx.x;
  if (i >= 4 * 256 * 256) return;
  int oc = i & 255, rest = i >> 8;
  int ic = rest & 255, kl = rest >> 8;
  wt[i] = w[(ic * 256 + oc) * 4 + kl];
}
__global__ void k_tw_conv2(const float* __restrict__ w, float* __restrict__ wt) {
  int i = blockIdx.x * 256 + threadIdx.x;
  if (i >= 256 * 256) return;
  int oc = i & 255, ic = i >> 8;
  wt[i] = w[oc * 256 + ic];
}

// ---------------- zero the pad columns of padded activation buffers ---------
__global__ void k_zpad(float* __restrict__ x0p, float* __restrict__ x1p) {
  int i = blockIdx.x * 256 + threadIdx.x;
  if (i >= 7340032) return;  // 2 * 128*256*28*4
  int b = (i >= 3670016) ? 1 : 0;
  int j = b ? (i - 3670016) : i;
  int col4 = j & 3;
  int rowidx = j >> 2;               // r*256*28 + ic*28 + h
  int col = (col4 == 0) ? 0 : (28 + col4);  // 0,29,30,31
  (b ? x1p : x0p)[(size_t)rowidx * 32 + col] = 0.f;
}

// ---------------- bilinear resize 56->28 ----------------
__device__ inline int resize_taps(int i, int* rows, float* wts) {
  if (i == 0) {
    rows[0] = 0; rows[1] = 1; rows[2] = 2;
    wts[0] = 3.f / 7.f; wts[1] = 3.f / 7.f; wts[2] = 1.f / 7.f; return 3;
  }
  if (i == 27) {
    rows[0] = 53; rows[1] = 54; rows[2] = 55;
    wts[0] = 1.f / 7.f; wts[1] = 3.f / 7.f; wts[2] = 3.f / 7.f; return 3;
  }
  rows[0] = 2 * i - 1; rows[1] = 2 * i; rows[2] = 2 * i + 1; rows[3] = 2 * i + 2;
  wts[0] = 0.125f; wts[1] = 0.375f; wts[2] = 0.375f; wts[3] = 0.125f; return 4;
}

__global__ __launch_bounds__(256) void k_resize(
    const float* __restrict__ ma_in, const float* __restrict__ mb_in,
    float* __restrict__ m_a28, float* __restrict__ m_b28,
    float* __restrict__ ma_sum) {
  int r = blockIdx.x, side = blockIdx.y, t = threadIdx.x;
  const float* in = (side ? mb_in : ma_in) + (size_t)r * 3136;
  float* out = (side ? m_b28 : m_a28) + (size_t)r * 784;
  float cnt = 0.f;
  for (int p = t; p < 784; p += 256) {
    int i = p / 28, j = p % 28;
    int rr_[4], cc_[4]; float wr[4], wc[4];
    int nr = resize_taps(i, rr_, wr), nc = resize_taps(j, cc_, wc);
    float v = 0.f;
    for (int a = 0; a < nr; ++a) {
      float rv = 0.f;
      for (int b = 0; b < nc; ++b) rv += wc[b] * in[rr_[a] * 56 + cc_[b]];
      v += wr[a] * rv;
    }
    out[p] = v;
    cnt += (v >= 0.f) ? 1.f : 0.f;
  }
  __shared__ float red[4];
  for (int off = 32; off; off >>= 1) cnt += __shfl_xor(cnt, off, 64);
  int lane = t & 63, wid = t >> 6;
  if (lane == 0) red[wid] = cnt;
  __syncthreads();
  if (t == 0 && side == 0) ma_sum[r] = red[0] + red[1] + red[2] + red[3];
}

// ---------------- gap + conv2(gap) ----------------
__global__ __launch_bounds__(256) void k_gap(
    const float* __restrict__ feat_a, const float* __restrict__ m_a28,
    const float* __restrict__ ma_sum, float* __restrict__ gap) {
  int r = blockIdx.y, wid = threadIdx.x >> 6, lane = threadIdx.x & 63;
  int c = blockIdx.x * 4 + wid;
  const float* x = feat_a + ((size_t)r * 256 + c) * 784;
  const float* m = m_a28 + (size_t)r * 784;
  float s = 0.f;
  for (int n = lane; n < 784; n += 64)
    s += x[n] * ((m[n] >= 0.f) ? 1.f : 0.f);
  for (int off = 32; off; off >>= 1) s += __shfl_xor(s, off, 64);
  if (lane == 0) gap[r * 256 + c] = s / (ma_sum[r] + 1e-5f);
}

__global__ __launch_bounds__(256) void k_gap2(
    const float* __restrict__ gap, const float* __restrict__ w2t,
    const float* __restrict__ b2, float* __restrict__ gap2) {
  int r = blockIdx.x, t = threadIdx.x;
  __shared__ float g[256];
  g[t] = gap[r * 256 + t];
  __syncthreads();
  float acc = b2[t];
  for (int ic = 0; ic < 256; ++ic) acc += w2t[ic * 256 + t] * g[ic];
  gap2[r * 256 + t] = acc;
}

// ---------------- EM: per-stage kernels ----------------
// mu layout: [r][256][8]; zk layout: [r][8][784]
__global__ __launch_bounds__(256) void k_em_init(
    const float* __restrict__ pos_mu, const float* __restrict__ neg_mu,
    float* __restrict__ mu) {
  int r = blockIdx.x, t = threadIdx.x;
  float* o = mu + (size_t)r * 2048 + t * 8;
#pragma unroll
  for (int k = 0; k < 4; ++k) {
    o[k] = pos_mu[t * 4 + k];
    o[k + 4] = neg_mu[t * 4 + k];
  }
}

// z-step: S = x^T mu, masked softmax(20*S) per side, store z (unnormalized over n)
__global__ __launch_bounds__(256) void k_em_A(
    const float* __restrict__ x, const float* __restrict__ mres,
    const float* __restrict__ mu, float* __restrict__ zk) {
  __shared__ __align__(16) float muL[256][8];
  int r = blockIdx.y, t = threadIdx.x;
  {
    const float4* src = (const float4*)(mu + (size_t)r * 2048);
    float4 a = src[t * 2], b = src[t * 2 + 1];
    *(float4*)&muL[t][0] = a; *(float4*)&muL[t][4] = b;
  }
  __syncthreads();
  if (t >= 196) return;
  int n = blockIdx.x * 196 + t;
  float m = (mres[(size_t)r * 784 + n] >= 0.f) ? 1.f : 0.f;
  const float* xp = x + (size_t)r * 200704 + n;
  float S[8] = {0, 0, 0, 0, 0, 0, 0, 0};
#pragma unroll 8
  for (int c = 0; c < 256; ++c) {
    float xv = xp[c * 784];
    float4 a = *(const float4*)&muL[c][0];
    float4 b = *(const float4*)&muL[c][4];
    S[0] += xv * a.x; S[1] += xv * a.y; S[2] += xv * a.z; S[3] += xv * a.w;
    S[4] += xv * b.x; S[5] += xv * b.y; S[6] += xv * b.z; S[7] += xv * b.w;
  }
  float mxp = fmaxf(fmaxf(S[0], S[1]), fmaxf(S[2], S[3]));
  float e0 = expf(20.f * (S[0] - mxp)), e1 = expf(20.f * (S[1] - mxp));
  float e2 = expf(20.f * (S[2] - mxp)), e3 = expf(20.f * (S[3] - mxp));
  float dp = m / (e0 + e1 + e2 + e3);
  float mxn = fmaxf(fmaxf(S[4], S[5]), fmaxf(S[6], S[7]));
  float f0 = expf(20.f * (S[4] - mxn)), f1 = expf(20.f * (S[5] - mxn));
  float f2 = expf(20.f * (S[6] - mxn)), f3 = expf(20.f * (S[7] - mxn));
  float dn = (1.f - m) / (f0 + f1 + f2 + f3);
  float* zp = zk + (size_t)r * 6272 + n;
  zp[0] = e0 * dp; zp[784] = e1 * dp; zp[1568] = e2 * dp; zp[2352] = e3 * dp;
  zp[3136] = f0 * dn; zp[3920] = f1 * dn; zp[4704] = f2 * dn; zp[5488] = f3 * dn;
}

// reduce-step: munew_raw[c][k] = sum_n x[c][n] z[k][n]
__global__ __launch_bounds__(256) void k_em_B(
    const float* __restrict__ x, const float* __restrict__ zk,
    float* __restrict__ munew) {
  int r = blockIdx.y, t = threadIdx.x;
  int lane = t & 63, wid = t >> 6;
  int cbase = blockIdx.x * 32 + wid * 8;
  const float4* x4 = (const float4*)(x + (size_t)r * 200704);
  const float4* z4 = (const float4*)(zk + (size_t)r * 6272);
  float acc[8][8];
#pragma unroll
  for (int c8 = 0; c8 < 8; ++c8)
#pragma unroll
    for (int k = 0; k < 8; ++k) acc[c8][k] = 0.f;
#pragma unroll
  for (int i = 0; i < 3; ++i) {
    int f = i * 64 + lane;
    float4 zv[8];
#pragma unroll
    for (int k = 0; k < 8; ++k) zv[k] = z4[k * 196 + f];
#pragma unroll
    for (int c8 = 0; c8 < 8; ++c8) {
      float4 xv = x4[(cbase + c8) * 196 + f];
#pragma unroll
      for (int k = 0; k < 8; ++k) {
        acc[c8][k] = fmaf(xv.x, zv[k].x, acc[c8][k]);
        acc[c8][k] = fmaf(xv.y, zv[k].y, acc[c8][k]);
        acc[c8][k] = fmaf(xv.z, zv[k].z, acc[c8][k]);
        acc[c8][k] = fmaf(xv.w, zv[k].w, acc[c8][k]);
      }
    }
  }
  if (lane < 4) {  // tail: float4 indices 192..195
    int f = 192 + lane;
    float4 zv[8];
#pragma unroll
    for (int k = 0; k < 8; ++k) zv[k] = z4[k * 196 + f];
#pragma unroll
    for (int c8 = 0; c8 < 8; ++c8) {
      float4 xv = x4[(cbase + c8) * 196 + f];
#pragma unroll
      for (int k = 0; k < 8; ++k) {
        acc[c8][k] = fmaf(xv.x, zv[k].x, acc[c8][k]);
        acc[c8][k] = fmaf(xv.y, zv[k].y, acc[c8][k]);
        acc[c8][k] = fmaf(xv.z, zv[k].z, acc[c8][k]);
        acc[c8][k] = fmaf(xv.w, zv[k].w, acc[c8][k]);
      }
    }
  }
#pragma unroll
  for (int c8 = 0; c8 < 8; ++c8)
#pragma unroll
    for (int k = 0; k < 8; ++k)
      for (int off = 32; off; off >>= 1)
        acc[c8][k] += __shfl_xor(acc[c8][k], off, 64);
  if (lane == 0) {
    float* o = munew + (size_t)r * 2048 + cbase * 8;
#pragma unroll
    for (int c8 = 0; c8 < 8; ++c8)
#pragma unroll
      for (int k = 0; k < 8; ++k) o[c8 * 8 + k] = acc[c8][k];
  }
}

// normalize-step: exact l1(cs) + l2 fold: mu = (munew*s)/(1e-6+||munew*s||), s=1/(1e-6+cs)
__global__ __launch_bounds__(512) void k_em_N(
    const float* __restrict__ munew, const float* __restrict__ zk,
    float* __restrict__ mu) {
  __shared__ float redsh[8][8];
  __shared__ float csv[8];
  __shared__ float inv[8];
  int r = blockIdx.x, t = threadIdx.x, lane = t & 63, wid = t >> 6;
  // cs[k]: wave k reduces zk row k
  {
    const float* zp = zk + ((size_t)r * 8 + wid) * 784;
    float cs = 0.f;
    for (int n = lane; n < 784; n += 64) cs += zp[n];
    for (int off = 32; off; off >>= 1) cs += __shfl_xor(cs, off, 64);
    if (lane == 0) csv[wid] = cs;
  }
  // sum of squares per k over c
  float sq[8];
  if (t < 256) {
    const float* mn = munew + (size_t)r * 2048 + t * 8;
#pragma unroll
    for (int k = 0; k < 8; ++k) { float v = mn[k]; sq[k] = v * v; }
  } else {
#pragma unroll
    for (int k = 0; k < 8; ++k) sq[k] = 0.f;
  }
#pragma unroll
  for (int k = 0; k < 8; ++k)
    for (int off = 32; off; off >>= 1) sq[k] += __shfl_xor(sq[k], off, 64);
  if (lane == 0) {
#pragma unroll
    for (int k = 0; k < 8; ++k) redsh[wid][k] = sq[k];
  }
  __syncthreads();
  if (t < 8) {
    float rn = 0.f;
#pragma unroll
    for (int w = 0; w < 8; ++w) rn += redsh[w][t];
    float s = 1.f / (1e-6f + csv[t]);
    inv[t] = s / (1e-6f + s * sqrtf(rn));
  }
  __syncthreads();
  if (t < 256) {
    const float* mn = munew + (size_t)r * 2048 + t * 8;
    float* o = mu + (size_t)r * 2048 + t * 8;
#pragma unroll
    for (int k = 0; k < 8; ++k) o[k] = mn[k] * inv[k];
  }
}

// prop: z = softmax_k(mu . xb) over all 8, write pos/neg sums
__global__ __launch_bounds__(256) void k_em_prop(
    const float* __restrict__ xb, const float* __restrict__ mu,
    float* __restrict__ pos_z, float* __restrict__ neg_z) {
  __shared__ __align__(16) float muL[256][8];
  int r = blockIdx.y, t = threadIdx.x;
  {
    const float4* src = (const float4*)(mu + (size_t)r * 2048);
    float4 a = src[t * 2], b = src[t * 2 + 1];
    *(float4*)&muL[t][0] = a; *(float4*)&muL[t][4] = b;
  }
  __syncthreads();
  if (t >= 196) return;
  int n = blockIdx.x * 196 + t;
  const float* xp = xb + (size_t)r * 200704 + n;
  float S[8] = {0, 0, 0, 0, 0, 0, 0, 0};
#pragma unroll 8
  for (int c = 0; c < 256; ++c) {
    float xv = xp[c * 784];
    float4 a = *(const float4*)&muL[c][0];
    float4 b = *(const float4*)&muL[c][4];
    S[0] += xv * a.x; S[1] += xv * a.y; S[2] += xv * a.z; S[3] += xv * a.w;
    S[4] += xv * b.x; S[5] += xv * b.y; S[6] += xv * b.z; S[7] += xv * b.w;
  }
  float mx = S[0];
#pragma unroll
  for (int k = 1; k < 8; ++k) mx = fmaxf(mx, S[k]);
  float e[8], d = 0.f;
#pragma unroll
  for (int k = 0; k < 8; ++k) { e[k] = expf(S[k] - mx); d += e[k]; }
  float invd = 1.f / d;
  pos_z[(size_t)r * 784 + n] = (e[0] + e[1] + e[2] + e[3]) * invd;
  neg_z[(size_t)r * 784 + n] = (e[4] + e[5] + e[6] + e[7]) * invd;
}

// ---------------- 3x3 conv (direct, f32) ----------------
// wt layout: [kh][kw][ic][oc]. Non-conv1 path: padded NCHW [r][ic][28][32],
// data at cols 1..28, pad cols zeroed. conv1 reads unpadded inputs w/ clamps.
template <int CIN, bool IS_CONV1, bool RELU>
__global__ __launch_bounds__(256) void k_conv3x3(
    const float* __restrict__ x, const float* __restrict__ pz,
    const float* __restrict__ nz, const float* __restrict__ mres,
    const float* __restrict__ wt, const float* __restrict__ bias,
    const float* __restrict__ gap2, float* __restrict__ out) {
  int r = blockIdx.y, h = blockIdx.x, t = threadIdx.x;
  int oc = (t & 63) * 4;
  int w0 = __builtin_amdgcn_readfirstlane((t >> 6) * 7);
  float acc[7][4];
#pragma unroll
  for (int j = 0; j < 7; ++j)
    acc[j][0] = acc[j][1] = acc[j][2] = acc[j][3] = 0.f;
  for (int kh = 0; kh < 3; ++kh) {
    int row = h + kh - 1;
    if (row < 0 || row >= 28) continue;
    const float* wb = wt + (size_t)kh * 3 * CIN * 256 + oc;
    for (int ic = 0; ic < CIN; ++ic) {
      float xv[9];
      if (IS_CONV1) {
        const float* xrow;
        if (ic >= 256) {
          const float* e = (ic == 256) ? pz : (ic == 257) ? nz : mres;
          xrow = e + (size_t)r * 784 + row * 28;
        } else {
          xrow = x + ((size_t)r * 256 + ic) * 784 + row * 28;
        }
#pragma unroll
        for (int m2 = 0; m2 < 9; ++m2) {
          int w = w0 + m2 - 1;
          int wcl = min(max(w, 0), 27);
          float v = xrow[wcl];
          xv[m2] = (w >= 0 && w < 28) ? v : 0.f;
        }
      } else {
        const float* xrow = x + ((size_t)(r * CIN + ic) * 28 + row) * 32 + w0;
#pragma unroll
        for (int m2 = 0; m2 < 9; ++m2) xv[m2] = xrow[m2];
      }
#pragma unroll
      for (int kw = 0; kw < 3; ++kw) {
        float4 wv = *(const float4*)(wb + ((size_t)kw * CIN + ic) * 256);
#pragma unroll
        for (int j = 0; j < 7; ++j) {
          float xvv = xv[j + kw];
          acc[j][0] += xvv * wv.x; acc[j][1] += xvv * wv.y;
          acc[j][2] += xvv * wv.z; acc[j][3] += xvv * wv.w;
        }
      }
    }
  }
#pragma unroll
  for (int u = 0; u < 4; ++u) {
    float b = bias[oc + u];
    if (IS_CONV1) b += gap2[r * 256 + oc + u];
    float* o = out + ((size_t)(r * 256 + oc + u) * 28 + h) * 32 + 1 + w0;
#pragma unroll
    for (int j = 0; j < 7; ++j) {
      float v = acc[j][u] + b;
      if (RELU) v = fmaxf(v, 0.f);
      o[j] = v;
    }
  }
}

// ---------------- fused deconv(2x2,s2) + relu + 1x1 logits ----------------
__global__ __launch_bounds__(256) void k_deconv_logits(
    const float* __restrict__ xp, const float* __restrict__ dwt,
    const float* __restrict__ db, const float* __restrict__ wlog,
    const float* __restrict__ lb, float* __restrict__ out) {
  __shared__ float X[256 * 28];
  int r = blockIdx.y, h = blockIdx.x, t = threadIdx.x;
  for (int i = t; i < 7168; i += 256) {
    int ic = i / 28, w = i - ic * 28;
    X[i] = xp[((size_t)(r * 256 + ic) * 28 + h) * 32 + 1 + w];
  }
  __syncthreads();
  int lane = t & 63, oc = lane * 4;
  int w0 = __builtin_amdgcn_readfirstlane((t >> 6) * 7);
  float b0 = db[oc], b1 = db[oc + 1], b2 = db[oc + 2], b3 = db[oc + 3];
  float l0 = wlog[oc], l1 = wlog[oc + 1], l2 = wlog[oc + 2], l3 = wlog[oc + 3];
  float lbv = lb[0];
  for (int kl = 0; kl < 4; ++kl) {
    float acc[7][4];
#pragma unroll
    for (int j = 0; j < 7; ++j)
      acc[j][0] = acc[j][1] = acc[j][2] = acc[j][3] = 0.f;
    const float* wb = dwt + (size_t)kl * 65536 + oc;
    for (int ic = 0; ic < 256; ++ic) {
      float4 wv = *(const float4*)(wb + ic * 256);
#pragma unroll
      for (int j = 0; j < 7; ++j) {
        float xv = X[ic * 28 + w0 + j];
        acc[j][0] += xv * wv.x; acc[j][1] += xv * wv.y;
        acc[j][2] += xv * wv.z; acc[j][3] += xv * wv.w;
      }
    }
    int k = kl >> 1, l = kl & 1;
#pragma unroll
    for (int j = 0; j < 7; ++j) {
      float s = l0 * fmaxf(acc[j][0] + b0, 0.f) + l1 * fmaxf(acc[j][1] + b1, 0.f) +
                l2 * fmaxf(acc[j][2] + b2, 0.f) + l3 * fmaxf(acc[j][3] + b3, 0.f);
      for (int off = 32; off; off >>= 1) s += __shfl_xor(s, off, 64);
      if (lane == 0)
        out[(size_t)r * 3136 + (2 * h + k) * 56 + 2 * (w0 + j) + l] = s + lbv;
    }
  }
}

// ---------------- launcher ----------------
extern "C" void kernel_launch(void* const* d_in, const int* in_sizes, int n_in,
                              void* d_out, int out_size, void* d_ws, size_t ws_size,
                              hipStream_t stream) {
  const float* feat_a = (const float*)d_in[0];
  const float* mask_a = (const float*)d_in[1];
  const float* feat_b = (const float*)d_in[2];
  const float* mask_b = (const float*)d_in[3];
  const float* pos_mu = (const float*)d_in[4];
  const float* neg_mu = (const float*)d_in[5];
  const float* conv1_w = (const float*)d_in[6];
  const float* conv1_b = (const float*)d_in[7];
  const float* conv2_w = (const float*)d_in[8];
  const float* conv2_b = (const float*)d_in[9];
  const float* convs_w = (const float*)d_in[10];
  const float* convs_b = (const float*)d_in[11];
  const float* deconv_w = (const float*)d_in[12];
  const float* deconv_b = (const float*)d_in[13];
  const float* logits_w = (const float*)d_in[14];
  const float* logits_b = (const float*)d_in[15];
  float* out = (float*)d_out;
  float* ws = (float*)d_ws;

  // workspace layout (floats)
  float* m_a28 = ws;                   // 100352
  float* m_b28 = m_a28 + 100352;       // 100352
  float* ma_sum = m_b28 + 100352;      // 128
  float* gap = ma_sum + 128;           // 32768
  float* gap2 = gap + 32768;           // 32768
  float* pos_z = gap2 + 32768;         // 100352
  float* neg_z = pos_z + 100352;       // 100352
  float* w1t = neg_z + 100352;         // 596736
  float* w3t = w1t + 596736;           // 1769472
  float* dwt = w3t + 1769472;          // 262144
  float* w2t = dwt + 262144;           // 65536
  float* mu = w2t + 65536;             // 262144
  float* munew = mu + 262144;          // 262144
  float* zk = munew + 262144;          // 802816
  float* x0p = zk + 802816;            // 29360128 (128*256*28*32)
  float* x1p = x0p + 29360128;         // 29360128

  k_tw_conv1<<<(9 * 259 * 256 + 255) / 256, 256, 0, stream>>>(conv1_w, w1t);
  k_tw_convs<<<(3 * 9 * 256 * 256 + 255) / 256, 256, 0, stream>>>(convs_w, w3t);
  k_tw_deconv<<<(4 * 256 * 256 + 255) / 256, 256, 0, stream>>>(deconv_w, dwt);
  k_tw_conv2<<<(256 * 256 + 255) / 256, 256, 0, stream>>>(conv2_w, w2t);
  k_zpad<<<(7340032 + 255) / 256, 256, 0, stream>>>(x0p, x1p);

  k_resize<<<dim3(128, 2), 256, 0, stream>>>(mask_a, mask_b, m_a28, m_b28, ma_sum);
  k_gap<<<dim3(64, 128), 256, 0, stream>>>(feat_a, m_a28, ma_sum, gap);
  k_gap2<<<128, 256, 0, stream>>>(gap, w2t, conv2_b, gap2);

  // EM: 2 phases x 6 stages, then prop
  k_em_init<<<128, 256, 0, stream>>>(pos_mu, neg_mu, mu);
  for (int phase = 0; phase < 2; ++phase) {
    const float* x = phase ? feat_b : feat_a;
    const float* mm = phase ? m_b28 : m_a28;
    for (int s = 0; s < 6; ++s) {
      k_em_A<<<dim3(4, 128), 256, 0, stream>>>(x, mm, mu, zk);
      k_em_B<<<dim3(8, 128), 256, 0, stream>>>(x, zk, munew);
      k_em_N<<<128, 512, 0, stream>>>(munew, zk, mu);
    }
  }
  k_em_prop<<<dim3(4, 128), 256, 0, stream>>>(feat_b, mu, pos_z, neg_z);

  // conv1 + gap2 broadcast (no relu) -> padded x0p
  k_conv3x3<259, true, false><<<dim3(28, 128), 256, 0, stream>>>(
      feat_b, pos_z, neg_z, m_a28, w1t, conv1_b, gap2, x0p);
  // 3x relu convs, padded ping-pong
  k_conv3x3<256, false, true><<<dim3(28, 128), 256, 0, stream>>>(
      x0p, nullptr, nullptr, nullptr, w3t + (size_t)0 * 9 * 256 * 256,
      convs_b + 0 * 256, nullptr, x1p);
  k_conv3x3<256, false, true><<<dim3(28, 128), 256, 0, stream>>>(
      x1p, nullptr, nullptr, nullptr, w3t + (size_t)1 * 9 * 256 * 256,
      convs_b + 1 * 256, nullptr, x0p);
  k_conv3x3<256, false, true><<<dim3(28, 128), 256, 0, stream>>>(
      x0p, nullptr, nullptr, nullptr, w3t + (size_t)2 * 9 * 256 * 256,
      convs_b + 2 * 256, nullptr, x1p);

  k_deconv_logits<<<dim3(28, 128), 256, 0, stream>>>(x1p, dwt, deconv_b,
                                                     logits_w, logits_b, out);
}

// Round 3
// 1824.404 us; speedup vs baseline: 6.6299x; 4.1052x over previous
//
#include <hip/hip_runtime.h>
#include <cstddef>

typedef unsigned short u16;
typedef unsigned int u32;
typedef __attribute__((ext_vector_type(8))) short short8;
typedef __attribute__((ext_vector_type(4))) float f32x4;
typedef __attribute__((ext_vector_type(4))) u32 u32x4;
typedef __attribute__((ext_vector_type(2))) u32 u32x2;

__device__ inline u16 f2bf(float x) {
  union { float f; u32 u; } v; v.f = x;
  u32 r = v.u + 0x7fffu + ((v.u >> 16) & 1u);
  return (u16)(r >> 16);
}
__device__ inline int swz_of(int pix) {
  return (((pix >> 5) & 1) << 2) ^ (pix & 7);
}
__device__ inline int swz_e(int e, int sw) {
  return (e < 32) ? (e ^ sw) : (e ^ (sw & 3));
}

// ---------------- weight packing (MFMA A-fragment order, bf16) ----------------
// layout: wpk[((kk*16 + ot)*64 + lane)*8 + j], A[row=oc=ot*16+(lane&15)][k]
__global__ void k_pack1(const float* __restrict__ w, u16* __restrict__ wpk) {
  int i = blockIdx.x * 256 + threadIdx.x;  // 81*16*512
  if (i >= 663552) return;
  int j = i & 7, l = (i >> 3) & 63, ot = (i >> 9) & 15, kk = i >> 13;
  int kq = kk / 9, ks = kk % 9;
  int ic = ks * 32 + (l >> 4) * 8 + j;
  int oc = ot * 16 + (l & 15);
  float v = (ic < 259) ? w[(oc * 259 + ic) * 9 + kq] : 0.f;
  wpk[i] = f2bf(v);
}
__global__ void k_pack3(const float* __restrict__ w, u16* __restrict__ wpk) {
  int i = blockIdx.x * 256 + threadIdx.x;  // 3*72*16*512
  if (i >= 1769472) return;
  int j = i & 7, l = (i >> 3) & 63, ot = (i >> 9) & 15, kk2 = i >> 13;
  int ll = kk2 / 72, kk = kk2 % 72;
  int kq = kk / 8, ks = kk % 8;
  int ic = ks * 32 + (l >> 4) * 8 + j;
  int oc = ot * 16 + (l & 15);
  wpk[i] = f2bf(w[((ll * 256 + oc) * 256 + ic) * 9 + kq]);
}
__global__ void k_packd(const float* __restrict__ w, u16* __restrict__ wpk) {
  int i = blockIdx.x * 256 + threadIdx.x;  // 32*16*512
  if (i >= 262144) return;
  int j = i & 7, l = (i >> 3) & 63, ot = (i >> 9) & 15, kk = i >> 13;
  int kl = kk / 8, ks = kk % 8;
  int ic = ks * 32 + (l >> 4) * 8 + j;
  int oc = ot * 16 + (l & 15);
  wpk[i] = f2bf(w[(ic * 256 + oc) * 4 + kl]);
}
__global__ void k_tw_conv2(const float* __restrict__ w, float* __restrict__ wt) {
  int i = blockIdx.x * 256 + threadIdx.x;
  if (i >= 256 * 256) return;
  int oc = i & 255, ic = i >> 8;
  wt[i] = w[oc * 256 + ic];
}

// ---------------- zero halos of NHWC-padded bf16 activation buffers ----------
template <int CH>
__global__ void k_halo(u16* __restrict__ X) {
  int i = blockIdx.x * 256 + threadIdx.x;
  const int CHB = CH / 8;
  if (i >= 128 * 176 * CHB) return;
  int e = i % CHB, q = i / CHB;
  int r = q / 176, p = q % 176;
  int row, col;
  if (p < 64) { row = (p >> 5) * 29; col = p & 31; }
  else { int q2 = p - 64; row = 1 + (q2 >> 2); int cc = q2 & 3; col = cc ? (28 + cc) : 0; }
  u32x4 z = {0, 0, 0, 0};
  *(u32x4*)&X[(((size_t)r * 30 + row) * 32 + col) * CH + e * 8] = z;
}

// ---------------- bilinear resize 56->28 ----------------
__device__ inline int resize_taps(int i, int* rows, float* wts) {
  if (i == 0) {
    rows[0] = 0; rows[1] = 1; rows[2] = 2;
    wts[0] = 3.f / 7.f; wts[1] = 3.f / 7.f; wts[2] = 1.f / 7.f; return 3;
  }
  if (i == 27) {
    rows[0] = 53; rows[1] = 54; rows[2] = 55;
    wts[0] = 1.f / 7.f; wts[1] = 3.f / 7.f; wts[2] = 3.f / 7.f; return 3;
  }
  rows[0] = 2 * i - 1; rows[1] = 2 * i; rows[2] = 2 * i + 1; rows[3] = 2 * i + 2;
  wts[0] = 0.125f; wts[1] = 0.375f; wts[2] = 0.375f; wts[3] = 0.125f; return 4;
}

__global__ __launch_bounds__(256) void k_resize(
    const float* __restrict__ ma_in, const float* __restrict__ mb_in,
    float* __restrict__ m_a28, float* __restrict__ m_b28,
    float* __restrict__ ma_sum) {
  int r = blockIdx.x, side = blockIdx.y, t = threadIdx.x;
  const float* in = (side ? mb_in : ma_in) + (size_t)r * 3136;
  float* out = (side ? m_b28 : m_a28) + (size_t)r * 784;
  float cnt = 0.f;
  for (int p = t; p < 784; p += 256) {
    int i = p / 28, j = p % 28;
    int rr_[4], cc_[4]; float wr[4], wc[4];
    int nr = resize_taps(i, rr_, wr), nc = resize_taps(j, cc_, wc);
    float v = 0.f;
    for (int a = 0; a < nr; ++a) {
      float rv = 0.f;
      for (int b = 0; b < nc; ++b) rv += wc[b] * in[rr_[a] * 56 + cc_[b]];
      v += wr[a] * rv;
    }
    out[p] = v;
    cnt += (v >= 0.f) ? 1.f : 0.f;
  }
  __shared__ float red[4];
  for (int off = 32; off; off >>= 1) cnt += __shfl_xor(cnt, off, 64);
  int lane = t & 63, wid = t >> 6;
  if (lane == 0) red[wid] = cnt;
  __syncthreads();
  if (t == 0 && side == 0) ma_sum[r] = red[0] + red[1] + red[2] + red[3];
}

// ---------------- gap + conv2(gap) ----------------
__global__ __launch_bounds__(256) void k_gap(
    const float* __restrict__ feat_a, const float* __restrict__ m_a28,
    const float* __restrict__ ma_sum, float* __restrict__ gap) {
  int r = blockIdx.y, wid = threadIdx.x >> 6, lane = threadIdx.x & 63;
  int c = blockIdx.x * 4 + wid;
  const float* x = feat_a + ((size_t)r * 256 + c) * 784;
  const float* m = m_a28 + (size_t)r * 784;
  float s = 0.f;
  for (int n = lane; n < 784; n += 64)
    s += x[n] * ((m[n] >= 0.f) ? 1.f : 0.f);
  for (int off = 32; off; off >>= 1) s += __shfl_xor(s, off, 64);
  if (lane == 0) gap[r * 256 + c] = s / (ma_sum[r] + 1e-5f);
}

__global__ __launch_bounds__(256) void k_gap2(
    const float* __restrict__ gap, const float* __restrict__ w2t,
    const float* __restrict__ b2, float* __restrict__ gap2) {
  int r = blockIdx.x, t = threadIdx.x;
  __shared__ float g[256];
  g[t] = gap[r * 256 + t];
  __syncthreads();
  float acc = b2[t];
  for (int ic = 0; ic < 256; ++ic) acc += w2t[ic * 256 + t] * g[ic];
  gap2[r * 256 + t] = acc;
}

// ---------------- EM: per-stage kernels ----------------
__global__ __launch_bounds__(256) void k_em_init(
    const float* __restrict__ pos_mu, const float* __restrict__ neg_mu,
    float* __restrict__ mu) {
  int r = blockIdx.x, t = threadIdx.x;
  float* o = mu + (size_t)r * 2048 + t * 8;
#pragma unroll
  for (int k = 0; k < 4; ++k) {
    o[k] = pos_mu[t * 4 + k];
    o[k + 4] = neg_mu[t * 4 + k];
  }
}

__global__ __launch_bounds__(256) void k_em_A(
    const float* __restrict__ x, const float* __restrict__ mres,
    const float* __restrict__ mu, float* __restrict__ zk) {
  __shared__ __align__(16) float muL[256][8];
  int r = blockIdx.y, t = threadIdx.x;
  {
    const float4* src = (const float4*)(mu + (size_t)r * 2048);
    float4 a = src[t * 2], b = src[t * 2 + 1];
    *(float4*)&muL[t][0] = a; *(float4*)&muL[t][4] = b;
  }
  __syncthreads();
  if (t >= 196) return;
  int n = blockIdx.x * 196 + t;
  float m = (mres[(size_t)r * 784 + n] >= 0.f) ? 1.f : 0.f;
  const float* xp = x + (size_t)r * 200704 + n;
  float S[8] = {0, 0, 0, 0, 0, 0, 0, 0};
#pragma unroll 8
  for (int c = 0; c < 256; ++c) {
    float xv = xp[c * 784];
    float4 a = *(const float4*)&muL[c][0];
    float4 b = *(const float4*)&muL[c][4];
    S[0] += xv * a.x; S[1] += xv * a.y; S[2] += xv * a.z; S[3] += xv * a.w;
    S[4] += xv * b.x; S[5] += xv * b.y; S[6] += xv * b.z; S[7] += xv * b.w;
  }
  float mxp = fmaxf(fmaxf(S[0], S[1]), fmaxf(S[2], S[3]));
  float e0 = expf(20.f * (S[0] - mxp)), e1 = expf(20.f * (S[1] - mxp));
  float e2 = expf(20.f * (S[2] - mxp)), e3 = expf(20.f * (S[3] - mxp));
  float dp = m / (e0 + e1 + e2 + e3);
  float mxn = fmaxf(fmaxf(S[4], S[5]), fmaxf(S[6], S[7]));
  float f0 = expf(20.f * (S[4] - mxn)), f1 = expf(20.f * (S[5] - mxn));
  float f2 = expf(20.f * (S[6] - mxn)), f3 = expf(20.f * (S[7] - mxn));
  float dn = (1.f - m) / (f0 + f1 + f2 + f3);
  float* zp = zk + (size_t)r * 6272 + n;
  zp[0] = e0 * dp; zp[784] = e1 * dp; zp[1568] = e2 * dp; zp[2352] = e3 * dp;
  zp[3136] = f0 * dn; zp[3920] = f1 * dn; zp[4704] = f2 * dn; zp[5488] = f3 * dn;
}

__global__ __launch_bounds__(256) void k_em_B(
    const float* __restrict__ x, const float* __restrict__ zk,
    float* __restrict__ munew) {
  int r = blockIdx.y, t = threadIdx.x;
  int lane = t & 63, wid = t >> 6;
  int cbase = blockIdx.x * 32 + wid * 8;
  const float4* x4 = (const float4*)(x + (size_t)r * 200704);
  const float4* z4 = (const float4*)(zk + (size_t)r * 6272);
  float acc[8][8];
#pragma unroll
  for (int c8 = 0; c8 < 8; ++c8)
#pragma unroll
    for (int k = 0; k < 8; ++k) acc[c8][k] = 0.f;
#pragma unroll
  for (int i = 0; i < 3; ++i) {
    int f = i * 64 + lane;
    float4 zv[8];
#pragma unroll
    for (int k = 0; k < 8; ++k) zv[k] = z4[k * 196 + f];
#pragma unroll
    for (int c8 = 0; c8 < 8; ++c8) {
      float4 xv = x4[(cbase + c8) * 196 + f];
#pragma unroll
      for (int k = 0; k < 8; ++k) {
        acc[c8][k] = fmaf(xv.x, zv[k].x, acc[c8][k]);
        acc[c8][k] = fmaf(xv.y, zv[k].y, acc[c8][k]);
        acc[c8][k] = fmaf(xv.z, zv[k].z, acc[c8][k]);
        acc[c8][k] = fmaf(xv.w, zv[k].w, acc[c8][k]);
      }
    }
  }
  if (lane < 4) {
    int f = 192 + lane;
    float4 zv[8];
#pragma unroll
    for (int k = 0; k < 8; ++k) zv[k] = z4[k * 196 + f];
#pragma unroll
    for (int c8 = 0; c8 < 8; ++c8) {
      float4 xv = x4[(cbase + c8) * 196 + f];
#pragma unroll
      for (int k = 0; k < 8; ++k) {
        acc[c8][k] = fmaf(xv.x, zv[k].x, acc[c8][k]);
        acc[c8][k] = fmaf(xv.y, zv[k].y, acc[c8][k]);
        acc[c8][k] = fmaf(xv.z, zv[k].z, acc[c8][k]);
        acc[c8][k] = fmaf(xv.w, zv[k].w, acc[c8][k]);
      }
    }
  }
#pragma unroll
  for (int c8 = 0; c8 < 8; ++c8)
#pragma unroll
    for (int k = 0; k < 8; ++k)
      for (int off = 32; off; off >>= 1)
        acc[c8][k] += __shfl_xor(acc[c8][k], off, 64);
  if (lane == 0) {
    float* o = munew + (size_t)r * 2048 + cbase * 8;
#pragma unroll
    for (int c8 = 0; c8 < 8; ++c8)
#pragma unroll
      for (int k = 0; k < 8; ++k) o[c8 * 8 + k] = acc[c8][k];
  }
}

__global__ __launch_bounds__(512) void k_em_N(
    const float* __restrict__ munew, const float* __restrict__ zk,
    float* __restrict__ mu) {
  __shared__ float redsh[8][8];
  __shared__ float csv[8];
  __shared__ float inv[8];
  int r = blockIdx.x, t = threadIdx.x, lane = t & 63, wid = t >> 6;
  {
    const float* zp = zk + ((size_t)r * 8 + wid) * 784;
    float cs = 0.f;
    for (int n = lane; n < 784; n += 64) cs += zp[n];
    for (int off = 32; off; off >>= 1) cs += __shfl_xor(cs, off, 64);
    if (lane == 0) csv[wid] = cs;
  }
  float sq[8];
  if (t < 256) {
    const float* mn = munew + (size_t)r * 2048 + t * 8;
#pragma unroll
    for (int k = 0; k < 8; ++k) { float v = mn[k]; sq[k] = v * v; }
  } else {
#pragma unroll
    for (int k = 0; k < 8; ++k) sq[k] = 0.f;
  }
#pragma unroll
  for (int k = 0; k < 8; ++k)
    for (int off = 32; off; off >>= 1) sq[k] += __shfl_xor(sq[k], off, 64);
  if (lane == 0) {
#pragma unroll
    for (int k = 0; k < 8; ++k) redsh[wid][k] = sq[k];
  }
  __syncthreads();
  if (t < 8) {
    float rn = 0.f;
#pragma unroll
    for (int w = 0; w < 8; ++w) rn += redsh[w][t];
    float s = 1.f / (1e-6f + csv[t]);
    inv[t] = s / (1e-6f + s * sqrtf(rn));
  }
  __syncthreads();
  if (t < 256) {
    const float* mn = munew + (size_t)r * 2048 + t * 8;
    float* o = mu + (size_t)r * 2048 + t * 8;
#pragma unroll
    for (int k = 0; k < 8; ++k) o[k] = mn[k] * inv[k];
  }
}

__global__ __launch_bounds__(256) void k_em_prop(
    const float* __restrict__ xb, const float* __restrict__ mu,
    float* __restrict__ pos_z, float* __restrict__ neg_z) {
  __shared__ __align__(16) float muL[256][8];
  int r = blockIdx.y, t = threadIdx.x;
  {
    const float4* src = (const float4*)(mu + (size_t)r * 2048);
    float4 a = src[t * 2], b = src[t * 2 + 1];
    *(float4*)&muL[t][0] = a; *(float4*)&muL[t][4] = b;
  }
  __syncthreads();
  if (t >= 196) return;
  int n = blockIdx.x * 196 + t;
  const float* xp = xb + (size_t)r * 200704 + n;
  float S[8] = {0, 0, 0, 0, 0, 0, 0, 0};
#pragma unroll 8
  for (int c = 0; c < 256; ++c) {
    float xv = xp[c * 784];
    float4 a = *(const float4*)&muL[c][0];
    float4 b = *(const float4*)&muL[c][4];
    S[0] += xv * a.x; S[1] += xv * a.y; S[2] += xv * a.z; S[3] += xv * a.w;
    S[4] += xv * b.x; S[5] += xv * b.y; S[6] += xv * b.z; S[7] += xv * b.w;
  }
  float mx = S[0];
#pragma unroll
  for (int k = 1; k < 8; ++k) mx = fmaxf(mx, S[k]);
  float e[8], d = 0.f;
#pragma unroll
  for (int k = 0; k < 8; ++k) { e[k] = expf(S[k] - mx); d += e[k]; }
  float invd = 1.f / d;
  pos_z[(size_t)r * 784 + n] = (e[0] + e[1] + e[2] + e[3]) * invd;
  neg_z[(size_t)r * 784 + n] = (e[4] + e[5] + e[6] + e[7]) * invd;
}

// ---------------- build conv1 input: NHWC-padded bf16 [r][30][32][288] ------
__global__ __launch_bounds__(256) void k_mkxin(
    const float* __restrict__ feat_b, const float* __restrict__ pos_z,
    const float* __restrict__ neg_z, const float* __restrict__ m_a28,
    u16* __restrict__ Xin) {
  __shared__ u16 tile[32][65];
  int pt = blockIdx.x, cb = blockIdx.y, r = blockIdx.z;
  int t = threadIdx.x, w = t >> 6, lane = t & 63;
  int p0 = pt * 56;
#pragma unroll
  for (int i2 = 0; i2 < 8; ++i2) {
    int cl = w * 8 + i2;
    float v = 0.f;
    if (lane < 56) {
      int n = p0 + lane;
      if (cb < 8) v = feat_b[((size_t)r * 256 + cb * 32 + cl) * 784 + n];
      else if (cl == 0) v = pos_z[(size_t)r * 784 + n];
      else if (cl == 1) v = neg_z[(size_t)r * 784 + n];
      else if (cl == 2) v = m_a28[(size_t)r * 784 + n];
    }
    tile[cl][lane] = f2bf(v);
  }
  __syncthreads();
  int pl = t >> 2, eo = t & 3;
  if (pl < 56) {
    int n = p0 + pl, row = n / 28 + 1, col = n % 28 + 1;
    __align__(16) u16 o[8];
#pragma unroll
    for (int j2 = 0; j2 < 8; ++j2) o[j2] = tile[eo * 8 + j2][pl];
    *(u32x4*)&Xin[(((size_t)r * 30 + row) * 32 + col) * 288 + cb * 32 + eo * 8] =
        *(u32x4*)o;
  }
}

// ---------------- MFMA 3x3 conv: implicit GEMM ----------------
// Xin: NHWC-padded [r][30][32][CH] bf16, wpk: A-frag packed, out NHWC-padded 256ch
template <int CH, bool IS1, bool RELU>
__global__ __launch_bounds__(256, 1) void k_convm(
    const u16* __restrict__ Xin, const u16* __restrict__ wpk,
    const float* __restrict__ bias, const float* __restrict__ gap2,
    u16* __restrict__ Xout) {
  const int CHB = CH / 8;
  const int KSPT = CH / 32;
  __shared__ __align__(16) u16 lds[192 * CH];
  int r = blockIdx.y, strip = blockIdx.x;
  int h0 = strip * 4;
  int t = threadIdx.x, w = t >> 6, lane = t & 63;
  size_t base_u = ((size_t)r * 30 + h0) * 32 * CH;
  const int NCH = 192 * CHB;
  for (int c = t; c < NCH; c += 256) {
    int pix = c / CHB, e = c - pix * CHB;
    u32x4 v = *(const u32x4*)&Xin[base_u + (size_t)pix * CH + e * 8];
    int ep = swz_e(e, swz_of(pix));
    *(u32x4*)&lds[(pix * CHB + ep) * 8] = v;
  }
  __syncthreads();
  int kb = lane >> 4;
  int pr = (lane & 15) >> 2, pc = lane & 3;
  f32x4 acc[4][7];
#pragma unroll
  for (int i = 0; i < 4; ++i)
#pragma unroll
    for (int p = 0; p < 7; ++p) acc[i][p] = f32x4{0.f, 0.f, 0.f, 0.f};
  const u16* wbase = wpk + ((size_t)(w * 4) * 64 + lane) * 8;
  for (int kq = 0; kq < 9; ++kq) {
    int dh = kq / 3, dw = kq % 3;
    int pixq = (pr + dh) * 32 + pc + dw;
    int pco[7], swo[7];
#pragma unroll
    for (int p = 0; p < 7; ++p) {
      int pix = pixq + 4 * p;
      pco[p] = pix * CHB;
      swo[p] = swz_of(pix);
    }
    for (int ks = 0; ks < KSPT; ++ks) {
      int kk = kq * KSPT + ks;
      short8 A[4];
#pragma unroll
      for (int i = 0; i < 4; ++i)
        A[i] = *(const short8*)(wbase + (size_t)(kk * 16 + i) * 512);
      int e = ks * 4 + kb;
#pragma unroll
      for (int p = 0; p < 7; ++p) {
        short8 B = *(const short8*)&lds[(pco[p] + swz_e(e, swo[p])) * 8];
#pragma unroll
        for (int i = 0; i < 4; ++i)
          acc[i][p] =
              __builtin_amdgcn_mfma_f32_16x16x32_bf16(A[i], B, acc[i][p], 0, 0, 0);
      }
    }
  }
  // epilogue: D row = kb*4+reg (oc), col = lane&15 (pixel)
#pragma unroll
  for (int i = 0; i < 4; ++i) {
    int oc = (w * 4 + i) * 16 + kb * 4;
    f32x4 bb = *(const f32x4*)&bias[oc];
    if (IS1) bb += *(const f32x4*)&gap2[r * 256 + oc];
#pragma unroll
    for (int p = 0; p < 7; ++p) {
      f32x4 v = acc[i][p] + bb;
      if (RELU) {
        v.x = fmaxf(v.x, 0.f); v.y = fmaxf(v.y, 0.f);
        v.z = fmaxf(v.z, 0.f); v.w = fmaxf(v.w, 0.f);
      }
      __align__(8) u16 o[4] = {f2bf(v.x), f2bf(v.y), f2bf(v.z), f2bf(v.w)};
      int orow = h0 + pr + 1, ocol = 4 * p + pc + 1;
      *(u32x2*)&Xout[(((size_t)r * 30 + orow) * 32 + ocol) * 256 + oc] = *(u32x2*)o;
    }
  }
}

// ---------------- MFMA deconv(2x2,s2) + relu + 1x1 logits ----------------
__global__ __launch_bounds__(256, 1) void k_deconvm(
    const u16* __restrict__ X, const u16* __restrict__ wpkd,
    const float* __restrict__ db, const float* __restrict__ lw,
    const float* __restrict__ lb, float* __restrict__ out) {
  __shared__ __align__(16) u16 lds[112 * 256];
  __shared__ float plog[4][112];
  int r = blockIdx.y, strip = blockIdx.x, h0 = strip * 4;
  int t = threadIdx.x, w = t >> 6, lane = t & 63;
  for (int c = t; c < 112 * 32; c += 256) {
    int ip = c >> 5, e = c & 31;
    int hh = ip / 28, ww = ip % 28;
    u32x4 v = *(const u32x4*)&X[(((size_t)r * 30 + h0 + hh + 1) * 32 + ww + 1) * 256 + e * 8];
    *(u32x4*)&lds[(ip * 32 + (e ^ swz_of(ip))) * 8] = v;
  }
  __syncthreads();
  int kb = lane >> 4, colp = lane & 15;
  float lbv = lb[0];
  f32x4 lw4[4], db4[4];
#pragma unroll
  for (int i = 0; i < 4; ++i) {
    int oc = (w * 4 + i) * 16 + kb * 4;
    lw4[i] = *(const f32x4*)&lw[oc];
    db4[i] = *(const f32x4*)&db[oc];
  }
  const u16* wbase = wpkd + ((size_t)(w * 4) * 64 + lane) * 8;
  for (int kl = 0; kl < 4; ++kl) {
    f32x4 acc[4][7];
#pragma unroll
    for (int i = 0; i < 4; ++i)
#pragma unroll
      for (int p = 0; p < 7; ++p) acc[i][p] = f32x4{0.f, 0.f, 0.f, 0.f};
    for (int ks = 0; ks < 8; ++ks) {
      int kk = kl * 8 + ks;
      short8 A[4];
#pragma unroll
      for (int i = 0; i < 4; ++i)
        A[i] = *(const short8*)(wbase + (size_t)(kk * 16 + i) * 512);
      int e = ks * 4 + kb;
#pragma unroll
      for (int p = 0; p < 7; ++p) {
        int ip = p * 16 + colp;
        short8 B = *(const short8*)&lds[((ip << 5) + (e ^ swz_of(ip))) * 8];
#pragma unroll
        for (int i = 0; i < 4; ++i)
          acc[i][p] =
              __builtin_amdgcn_mfma_f32_16x16x32_bf16(A[i], B, acc[i][p], 0, 0, 0);
      }
    }
#pragma unroll
    for (int p = 0; p < 7; ++p) {
      float s = 0.f;
#pragma unroll
      for (int i = 0; i < 4; ++i) {
        f32x4 v = acc[i][p] + db4[i];
        s += lw4[i].x * fmaxf(v.x, 0.f) + lw4[i].y * fmaxf(v.y, 0.f) +
             lw4[i].z * fmaxf(v.z, 0.f) + lw4[i].w * fmaxf(v.w, 0.f);
      }
      s += __shfl_xor(s, 16, 64);
      s += __shfl_xor(s, 32, 64);
      if (lane < 16) plog[w][p * 16 + lane] = s;
    }
    __syncthreads();
    if (t < 112) {
      float s = plog[0][t] + plog[1][t] + plog[2][t] + plog[3][t] + lbv;
      int hh = t / 28, ww = t % 28;
      int k = kl >> 1, l = kl & 1;
      out[(size_t)r * 3136 + (2 * (h0 + hh) + k) * 56 + 2 * ww + l] = s;
    }
    __syncthreads();
  }
}

// ---------------- launcher ----------------
extern "C" void kernel_launch(void* const* d_in, const int* in_sizes, int n_in,
                              void* d_out, int out_size, void* d_ws, size_t ws_size,
                              hipStream_t stream) {
  const float* feat_a = (const float*)d_in[0];
  const float* mask_a = (const float*)d_in[1];
  const float* feat_b = (const float*)d_in[2];
  const float* mask_b = (const float*)d_in[3];
  const float* pos_mu = (const float*)d_in[4];
  const float* neg_mu = (const float*)d_in[5];
  const float* conv1_w = (const float*)d_in[6];
  const float* conv1_b = (const float*)d_in[7];
  const float* conv2_w = (const float*)d_in[8];
  const float* conv2_b = (const float*)d_in[9];
  const float* convs_w = (const float*)d_in[10];
  const float* convs_b = (const float*)d_in[11];
  const float* deconv_w = (const float*)d_in[12];
  const float* deconv_b = (const float*)d_in[13];
  const float* logits_w = (const float*)d_in[14];
  const float* logits_b = (const float*)d_in[15];
  float* out = (float*)d_out;

  char* P = (char*)d_ws;
  auto alloc = [&](size_t bytes) {
    char* q = P;
    P += (bytes + 255) & ~(size_t)255;
    return q;
  };
  float* m_a28 = (float*)alloc(401408 * 4);
  float* m_b28 = (float*)alloc(401408 * 4);
  float* ma_sum = (float*)alloc(512);
  float* gap = (float*)alloc(131072 * 4);
  float* gap2 = (float*)alloc(131072 * 4);
  float* pos_z = (float*)alloc(401408 * 4);
  float* neg_z = (float*)alloc(401408 * 4);
  float* w2t = (float*)alloc(65536 * 4);
  float* mu = (float*)alloc(262144 * 4);
  float* munew = (float*)alloc(262144 * 4);
  float* zk = (float*)alloc(802816 * 4);
  u16* wpk1 = (u16*)alloc(663552 * 2);
  u16* wpk3 = (u16*)alloc(1769472 * 2);
  u16* wpkd = (u16*)alloc(262144 * 2);
  u16* Xin = (u16*)alloc((size_t)128 * 30 * 32 * 288 * 2);
  u16* A1 = (u16*)alloc((size_t)128 * 30 * 32 * 256 * 2);
  u16* A2 = (u16*)alloc((size_t)128 * 30 * 32 * 256 * 2);

  // weight packs (independent)
  k_pack1<<<2592, 256, 0, stream>>>(conv1_w, wpk1);
  k_pack3<<<6912, 256, 0, stream>>>(convs_w, wpk3);
  k_packd<<<1024, 256, 0, stream>>>(deconv_w, wpkd);
  k_tw_conv2<<<256, 256, 0, stream>>>(conv2_w, w2t);
  // halo zeros
  k_halo<288><<<3168, 256, 0, stream>>>(Xin);
  k_halo<256><<<2816, 256, 0, stream>>>(A1);
  k_halo<256><<<2816, 256, 0, stream>>>(A2);

  k_resize<<<dim3(128, 2), 256, 0, stream>>>(mask_a, mask_b, m_a28, m_b28, ma_sum);
  k_gap<<<dim3(64, 128), 256, 0, stream>>>(feat_a, m_a28, ma_sum, gap);
  k_gap2<<<128, 256, 0, stream>>>(gap, w2t, conv2_b, gap2);

  k_em_init<<<128, 256, 0, stream>>>(pos_mu, neg_mu, mu);
  for (int phase = 0; phase < 2; ++phase) {
    const float* x = phase ? feat_b : feat_a;
    const float* mm = phase ? m_b28 : m_a28;
    for (int s = 0; s < 6; ++s) {
      k_em_A<<<dim3(4, 128), 256, 0, stream>>>(x, mm, mu, zk);
      k_em_B<<<dim3(8, 128), 256, 0, stream>>>(x, zk, munew);
      k_em_N<<<128, 512, 0, stream>>>(munew, zk, mu);
    }
  }
  k_em_prop<<<dim3(4, 128), 256, 0, stream>>>(feat_b, mu, pos_z, neg_z);

  k_mkxin<<<dim3(14, 9, 128), 256, 0, stream>>>(feat_b, pos_z, neg_z, m_a28, Xin);

  k_convm<288, true, false><<<dim3(7, 128), 256, 0, stream>>>(
      Xin, wpk1, conv1_b, gap2, A1);
  k_convm<256, false, true><<<dim3(7, 128), 256, 0, stream>>>(
      A1, wpk3, convs_b, nullptr, A2);
  k_convm<256, false, true><<<dim3(7, 128), 256, 0, stream>>>(
      A2, wpk3 + 589824, convs_b + 256, nullptr, A1);
  k_convm<256, false, true><<<dim3(7, 128), 256, 0, stream>>>(
      A1, wpk3 + 2 * 589824, convs_b + 512, nullptr, A2);

  k_deconvm<<<dim3(7, 128), 256, 0, stream>>>(A2, wpkd, deconv_b, logits_w,
                                              logits_b, out);
}